// Round 26
// baseline (281.038 us; speedup 1.0000x reference)
//
#include <hip/hip_runtime.h>
#include <cstdint>
#include <cstddef>

typedef __bf16 bf16x8 __attribute__((ext_vector_type(8)));
typedef float f32x4 __attribute__((ext_vector_type(4)));

static __device__ __forceinline__ f32x4 mfma16(bf16x8 a, bf16x8 b, f32x4 c) {
  return __builtin_amdgcn_mfma_f32_16x16x32_bf16(a, b, c, 0, 0, 0);
}

// LAW (R19/R20 proven): compute kernels must NEVER vector-load from d_in —
// d_in is only touched by scalar-load kernels; all bf16x8 loads hit ws.

// ---------------- input dtype sniffing (proven) ----------------
__global__ __launch_bounds__(256) void detect_k(const uint32_t* __restrict__ hs,
                                                int* __restrict__ flag) {
  __shared__ int cnt;
  if (threadIdx.x == 0) cnt = 0;
  __syncthreads();
  uint32_t w = hs[threadIdx.x];
  int b = (w >> 8) & 0x7F;
  if (b >= 0x3C && b <= 0x40) atomicAdd(&cnt, 1);
  __syncthreads();
  if (threadIdx.x == 0) *flag = (cnt >= 128) ? 1 : 0;
}

// ---------------- dtype-adaptive converters (proven; SCALAR d_in reads) ----------
__global__ __launch_bounds__(256) void cvt_to_bf16_k(const void* __restrict__ src,
                                                     size_t srcOff,
                                                     __bf16* __restrict__ dst, int n,
                                                     const int* __restrict__ flag) {
  int i = blockIdx.x * 256 + threadIdx.x;
  if (i >= n) return;
  float v = (*flag) ? (float)((const __bf16*)src)[srcOff + i]
                    : ((const float*)src)[srcOff + i];
  dst[i] = (__bf16)v;
}

__global__ __launch_bounds__(256) void cvt_to_f32_k(const void* __restrict__ src,
                                                    float* __restrict__ dst, int n,
                                                    const int* __restrict__ flag) {
  int i = blockIdx.x * 256 + threadIdx.x;
  if (i >= n) return;
  dst[i] = (*flag) ? (float)((const __bf16*)src)[i] : ((const float*)src)[i];
}

// MgT[h][e][d] = M[h][d][e]
__global__ __launch_bounds__(256) void cvt_MgT_k(const void* __restrict__ src,
                                                 __bf16* __restrict__ dst,
                                                 const int* __restrict__ flag) {
  int i = blockIdx.x * 256 + threadIdx.x;
  if (i >= 65536) return;
  int h = i >> 12, rem = i & 4095, e = rem >> 6, d = rem & 63;
  size_t sidx = (size_t)h * 4096 + d * 64 + e;
  float v = (*flag) ? (float)((const __bf16*)src)[sidx] : ((const float*)src)[sidx];
  dst[i] = (__bf16)v;
}

// Transposing weight converter (R24-proven): W -> Wt[n][k] in ws.
__global__ void cvt_wT_k(const void* __restrict__ W, __bf16* __restrict__ T,
                         const int* __restrict__ flag) {
  __shared__ __bf16 t[32][33];
  int k0 = blockIdx.x * 32, n0 = blockIdx.y * 32;
  int tx = threadIdx.x, ty = threadIdx.y;
  int f = *flag;
#pragma unroll
  for (int i = 0; i < 32; i += 8) {
    size_t idx = (size_t)(k0 + ty + i) * 1024 + n0 + tx;
    float v = f ? (float)((const __bf16*)W)[idx] : ((const float*)W)[idx];
    t[ty + i][tx] = (__bf16)v;
  }
  __syncthreads();
#pragma unroll
  for (int i = 0; i < 32; i += 8)
    T[(size_t)(n0 + ty + i) * 1024 + k0 + tx] = t[tx][ty + i];
}

// ---------------- V transpose to global (R25-proven) ----------------
__global__ __launch_bounds__(256) void vt2_k(const __bf16* __restrict__ qkv2,
                                             __bf16* __restrict__ Vt2) {
  __shared__ __bf16 t[64][72];
  const int h = blockIdx.x, k0 = blockIdx.y * 64, bl = blockIdx.z;
  const int tid = threadIdx.x;
  const int r = tid >> 2, dc = (tid & 3) * 16;
  const __bf16* src = qkv2 + (size_t)(bl * 1024 + k0 + r) * 3072 + 2048 + h * 64 + dc;
  *(bf16x8*)(&t[r][dc]) = *(const bf16x8*)(src);
  *(bf16x8*)(&t[r][dc + 8]) = *(const bf16x8*)(src + 8);
  __syncthreads();
  const int dr = tid >> 2, kc = (tid & 3) * 16;
  __bf16* dst = Vt2 + ((size_t)(bl * 16 + h) * 64 + dr) * 1024 + k0 + kc;
  bf16x8 o0, o1;
#pragma unroll
  for (int j = 0; j < 8; ++j) { o0[j] = t[kc + j][dr]; o1[j] = t[kc + 8 + j][dr]; }
  *(bf16x8*)dst = o0;
  *(bf16x8*)(dst + 8) = o1;
}

// ---------------- m92 XOR-swizzled GEMM (R24-proven) ----------------
__global__ __launch_bounds__(256) void gemm_bt_k(const __bf16* __restrict__ A,
                                                 const __bf16* __restrict__ Bt,
                                                 const float* __restrict__ bias,
                                                 __bf16* __restrict__ C,
                                                 int M, int N, int K, int ldc) {
  const int tm = blockIdx.x * 128, tn = blockIdx.y * 128;
  const int tid = threadIdx.x;
  const int w = tid >> 6, l = tid & 63;
  const int l15 = l & 15, l4 = l >> 4;
  const int wm = (w >> 1) * 64, wn = (w & 1) * 64;
  __shared__ __bf16 As[128 * 64];
  __shared__ __bf16 Bs[128 * 64];
  f32x4 acc[4][4] = {};
  for (int kt = 0; kt < K; kt += 64) {
    __syncthreads();
#pragma unroll
    for (int i = 0; i < 4; ++i) {
      int c = tid + i * 256;
      int r = c >> 3, s = c & 7;
      int byt = r * 128 + ((s ^ (r & 7)) << 4);
      *(bf16x8*)((char*)As + byt) = *(const bf16x8*)(A + (size_t)(tm + r) * K + kt + s * 8);
      *(bf16x8*)((char*)Bs + byt) = *(const bf16x8*)(Bt + (size_t)(tn + r) * K + kt + s * 8);
    }
    __syncthreads();
#pragma unroll
    for (int kk = 0; kk < 2; ++kk) {
      bf16x8 af[4], bfr[4];
#pragma unroll
      for (int m = 0; m < 4; ++m) {
        int row = wm + m * 16 + l15;
        af[m] = *(const bf16x8*)((char*)As + row * 128 + (((l4 + 4 * kk) ^ (row & 7)) << 4));
      }
#pragma unroll
      for (int n = 0; n < 4; ++n) {
        int row = wn + n * 16 + l15;
        bfr[n] = *(const bf16x8*)((char*)Bs + row * 128 + (((l4 + 4 * kk) ^ (row & 7)) << 4));
      }
#pragma unroll
      for (int m = 0; m < 4; ++m)
#pragma unroll
        for (int n = 0; n < 4; ++n)
          acc[m][n] = mfma16(af[m], bfr[n], acc[m][n]);
    }
  }
#pragma unroll
  for (int m = 0; m < 4; ++m)
#pragma unroll
    for (int n = 0; n < 4; ++n) {
      int row = tm + wm + m * 16 + l4 * 4;
      int col = tn + wn + n * 16 + l15;
      float bb = bias[col];
#pragma unroll
      for (int r = 0; r < 4; ++r)
        C[(size_t)(row + r) * ldc + col] = (__bf16)(acc[m][n][r] + bb);
    }
}

__global__ __launch_bounds__(256) void gemm_bt_out_k(const __bf16* __restrict__ A,
                                                     const __bf16* __restrict__ Bt,
                                                     const float* __restrict__ bias,
                                                     void* __restrict__ out,
                                                     int M, int N, int K, int pairOff,
                                                     const int* __restrict__ flag) {
  const int tm = blockIdx.x * 128, tn = blockIdx.y * 128;
  const int tid = threadIdx.x;
  const int w = tid >> 6, l = tid & 63;
  const int l15 = l & 15, l4 = l >> 4;
  const int wm = (w >> 1) * 64, wn = (w & 1) * 64;
  __shared__ __bf16 As[128 * 64];
  __shared__ __bf16 Bs[128 * 64];
  f32x4 acc[4][4] = {};
  for (int kt = 0; kt < K; kt += 64) {
    __syncthreads();
#pragma unroll
    for (int i = 0; i < 4; ++i) {
      int c = tid + i * 256;
      int r = c >> 3, s = c & 7;
      int byt = r * 128 + ((s ^ (r & 7)) << 4);
      *(bf16x8*)((char*)As + byt) = *(const bf16x8*)(A + (size_t)(tm + r) * K + kt + s * 8);
      *(bf16x8*)((char*)Bs + byt) = *(const bf16x8*)(Bt + (size_t)(tn + r) * K + kt + s * 8);
    }
    __syncthreads();
#pragma unroll
    for (int kk = 0; kk < 2; ++kk) {
      bf16x8 af[4], bfr[4];
#pragma unroll
      for (int m = 0; m < 4; ++m) {
        int row = wm + m * 16 + l15;
        af[m] = *(const bf16x8*)((char*)As + row * 128 + (((l4 + 4 * kk) ^ (row & 7)) << 4));
      }
#pragma unroll
      for (int n = 0; n < 4; ++n) {
        int row = wn + n * 16 + l15;
        bfr[n] = *(const bf16x8*)((char*)Bs + row * 128 + (((l4 + 4 * kk) ^ (row & 7)) << 4));
      }
#pragma unroll
      for (int m = 0; m < 4; ++m)
#pragma unroll
        for (int n = 0; n < 4; ++n)
          acc[m][n] = mfma16(af[m], bfr[n], acc[m][n]);
    }
  }
  int use16 = *flag;
#pragma unroll
  for (int m = 0; m < 4; ++m)
#pragma unroll
    for (int n = 0; n < 4; ++n) {
      int row = tm + wm + m * 16 + l4 * 4;
      int col = tn + wn + n * 16 + l15;
      float bb = bias[col];
#pragma unroll
      for (int r = 0; r < 4; ++r) {
        float v = acc[m][n][r] + bb;
        size_t idx = (size_t)(pairOff + row + r) * N + col;
        if (use16) ((__bf16*)out)[idx] = (__bf16)v;
        else       ((float*)out)[idx] = v;
      }
    }
}

// ---------------- MFMA fused attention: bf16 RKb (3 blocks/CU) + swizzled Pl -------
__global__ __launch_bounds__(256) void attn_fused_k(const __bf16* __restrict__ QKV2,
                                                    const __bf16* __restrict__ Vt2,
                                                    const float* __restrict__ amask,
                                                    const __bf16* __restrict__ rel16,
                                                    const __bf16* __restrict__ MgT16,
                                                    const float* __restrict__ zg32,
                                                    const float* __restrict__ ga32,
                                                    __bf16* __restrict__ comb) {
  const int qt = blockIdx.x, bh = blockIdx.y;
  const int bl = bh >> 4, h = bh & 15;
  const int tid = threadIdx.x;
  const int w = tid >> 6, l = tid & 63;
  const int l15 = l & 15, l4 = l >> 4;
  const int q0 = qt * 64;
  const __bf16* QKVb = QKV2 + (size_t)bl * 1024 * 3072;
  const __bf16* VtH = Vt2 + (size_t)(bl * 16 + h) * 64 * 1024;

  __shared__ __bf16 Kt[64][72];      // 9216 B  (epilogue: sqb overlay)
  __shared__ __bf16 VtT[64][72];     // 9216 B  (epilogue: Mtb overlay)
  __shared__ __bf16 Pl[4][16 * 72];  // 9216 B  (XOR-swizzled)
  __shared__ __bf16 RKb16[128 * 66]; // 16896 B (bf16 rel@K; ~2-way reads)
  __shared__ float maskv[64];
  __shared__ float denv[64];

  bf16x8 qf[2];
#pragma unroll
  for (int kk = 0; kk < 2; ++kk)
    qf[kk] = *(const bf16x8*)(QKVb + (size_t)(q0 + w * 16 + l15) * 3072 + h * 64 +
                              l4 * 8 + kk * 32);

  f32x4 accO[4] = {};
  float mrun[4], lrun[4];
#pragma unroll
  for (int r = 0; r < 4; ++r) { mrun[r] = -3.0e38f; lrun[r] = 0.f; }

  char* PlW = (char*)&Pl[w][0];

  for (int kt = 0; kt < 16; ++kt) {
    const int k0 = kt * 64;
    __syncthreads();
#pragma unroll
    for (int i = 0; i < 2; ++i) {
      int c = tid + i * 256;
      int kr = c >> 3, s = (c & 7) * 8;
      *(bf16x8*)(&Kt[kr][s]) =
          *(const bf16x8*)(QKVb + (size_t)(k0 + kr) * 3072 + 1024 + h * 64 + s);
      *(bf16x8*)(&VtT[kr][s]) = *(const bf16x8*)(VtH + (size_t)kr * 1024 + k0 + s);
    }
    if (tid < 64) maskv[tid] = amask[bl * 1024 + k0 + tid];
    __syncthreads();

    const int jb = q0 - k0 - 63 + 1024;
#pragma unroll
    for (int ms = 0; ms < 2; ++ms) {
      f32x4 rk[4] = {};
#pragma unroll
      for (int kk = 0; kk < 2; ++kk) {
        bf16x8 ea = *(const bf16x8*)(rel16 + (size_t)(jb + w * 32 + ms * 16 + l15) * 64 +
                                     l4 * 8 + kk * 32);
#pragma unroll
        for (int nb = 0; nb < 4; ++nb) {
          bf16x8 kb = *(const bf16x8*)(&Kt[nb * 16 + l15][l4 * 8 + kk * 32]);
          rk[nb] = mfma16(ea, kb, rk[nb]);
        }
      }
#pragma unroll
      for (int nb = 0; nb < 4; ++nb)
#pragma unroll
        for (int r = 0; r < 4; ++r)
          RKb16[(w * 32 + ms * 16 + l4 * 4 + r) * 66 + nb * 16 + l15] =
              (__bf16)rk[nb][r];
    }
    __syncthreads();

    f32x4 sacc[4] = {};
#pragma unroll
    for (int kk = 0; kk < 2; ++kk)
#pragma unroll
      for (int nb = 0; nb < 4; ++nb) {
        bf16x8 kb = *(const bf16x8*)(&Kt[nb * 16 + l15][l4 * 8 + kk * 32]);
        sacc[nb] = mfma16(qf[kk], kb, sacc[nb]);
      }

    float p[4][4];
    float tmax[4];
#pragma unroll
    for (int r = 0; r < 4; ++r) tmax[r] = -3.0e38f;
#pragma unroll
    for (int nb = 0; nb < 4; ++nb) {
      int kloc = nb * 16 + l15;
      float mk = maskv[kloc] * (-1e9f);
#pragma unroll
      for (int r = 0; r < 4; ++r) {
        int jl = (w * 16 + l4 * 4 + r) - kloc + 63;
        float s = (sacc[nb][r] + (float)RKb16[jl * 66 + kloc]) * 0.125f + mk;
        p[nb][r] = s;
        tmax[r] = fmaxf(tmax[r], s);
      }
    }
#pragma unroll
    for (int x = 1; x < 16; x <<= 1)
#pragma unroll
      for (int r = 0; r < 4; ++r) tmax[r] = fmaxf(tmax[r], __shfl_xor(tmax[r], x, 64));
    float al[4];
#pragma unroll
    for (int r = 0; r < 4; ++r) {
      float mn = fmaxf(mrun[r], tmax[r]);
      al[r] = __expf(mrun[r] - mn);
      mrun[r] = mn;
    }
    float rs[4] = {0.f, 0.f, 0.f, 0.f};
#pragma unroll
    for (int nb = 0; nb < 4; ++nb)
#pragma unroll
      for (int r = 0; r < 4; ++r) {
        p[nb][r] = __expf(p[nb][r] - mrun[r]);
        rs[r] += p[nb][r];
      }
#pragma unroll
    for (int x = 1; x < 16; x <<= 1)
#pragma unroll
      for (int r = 0; r < 4; ++r) rs[r] += __shfl_xor(rs[r], x, 64);
#pragma unroll
    for (int r = 0; r < 4; ++r) lrun[r] = lrun[r] * al[r] + rs[r];
#pragma unroll
    for (int nb = 0; nb < 4; ++nb)
#pragma unroll
      for (int r = 0; r < 4; ++r) accO[nb][r] *= al[r];

    // P -> per-wave LDS transpose, XOR-swizzled: byte ^= ((row>>2)<<5)
#pragma unroll
    for (int nb = 0; nb < 4; ++nb)
#pragma unroll
      for (int r = 0; r < 4; ++r) {
        int prow = l4 * 4 + r;
        int pcol = nb * 16 + l15;
        *(__bf16*)(PlW + prow * 144 + ((pcol * 2) ^ ((prow >> 2) << 5))) =
            (__bf16)p[nb][r];
      }
    __syncthreads();

#pragma unroll
    for (int kk = 0; kk < 2; ++kk) {
      bf16x8 pa = *(const bf16x8*)(PlW + l15 * 144 +
                                   ((kk * 64 + l4 * 16) ^ ((l15 >> 2) << 5)));
#pragma unroll
      for (int nb = 0; nb < 4; ++nb) {
        bf16x8 vb = *(const bf16x8*)(&VtT[nb * 16 + l15][kk * 32 + l4 * 8]);
        accO[nb] = mfma16(pa, vb, accO[nb]);
      }
    }
  }

#pragma unroll
  for (int nb = 0; nb < 4; ++nb)
#pragma unroll
    for (int r = 0; r < 4; ++r) accO[nb][r] /= lrun[r];

  // ---- epilogue: sqb overlays Kt, Mtb overlays VtT (both dead) ----
  __syncthreads();
  __bf16* sqb = &Kt[0][0];
  __bf16* Mtb = &VtT[0][0];
#pragma unroll
  for (int i = 0; i < 2; ++i) {
    int c = tid + i * 256;
    int qr = c >> 3, s = (c & 7) * 8;
    bf16x8 qv = *(const bf16x8*)(QKVb + (size_t)(q0 + qr) * 3072 + h * 64 + s);
#pragma unroll
    for (int j = 0; j < 8; ++j) {
      float x = (float)qv[j];
      sqb[qr * 72 + s + j] = (__bf16)(x > 0.f ? x + 1.f : __expf(x));
    }
    bf16x8 mv = *(const bf16x8*)(MgT16 + (size_t)h * 4096 + qr * 64 + s);
    *(bf16x8*)(&Mtb[qr * 72 + s]) = mv;
  }
  __syncthreads();
  if (tid < 64) {
    float sden = 0.f;
    const float* zp = zg32 + h * 64;
#pragma unroll
    for (int d = 0; d < 64; ++d) sden += (float)sqb[tid * 72 + d] * zp[d];
    denv[tid] = sden + 1e-6f;
  }
  __syncthreads();
  float gate = 1.f / (1.f + __expf(-ga32[0]));
  f32x4 nacc[4] = {};
#pragma unroll
  for (int kk = 0; kk < 2; ++kk) {
    bf16x8 sa = *(const bf16x8*)(sqb + (w * 16 + l15) * 72 + kk * 32 + l4 * 8);
#pragma unroll
    for (int nb = 0; nb < 4; ++nb) {
      bf16x8 mb = *(const bf16x8*)(Mtb + (nb * 16 + l15) * 72 + kk * 32 + l4 * 8);
      nacc[nb] = mfma16(sa, mb, nacc[nb]);
    }
  }
#pragma unroll
  for (int nb = 0; nb < 4; ++nb)
#pragma unroll
    for (int r = 0; r < 4; ++r) {
      int qrel = w * 16 + l4 * 4 + r;
      float gl = nacc[nb][r] / denv[qrel];
      float cv = gate * accO[nb][r] + (1.f - gate) * gl;
      comb[(size_t)(bl * 1024 + q0 + qrel) * 1024 + h * 64 + nb * 16 + l15] = (__bf16)cv;
    }
}

// ---------------- launcher ----------------
extern "C" void kernel_launch(void* const* d_in, const int* in_sizes, int n_in,
                              void* d_out, int out_size, void* d_ws, size_t ws_size,
                              hipStream_t stream) {
  const int expect[14] = {4194304, 4096, 1048576, 1024, 1048576, 1024, 1048576,
                          1024, 1048576, 1024, 131136, 65536, 1024, 1};
  if (n_in != 14) return;
  for (int i = 0; i < 14; ++i)
    if (in_sizes[i] != expect[i]) return;

  char* ws = (char*)d_ws;
  int*    flag   = (int*)ws;                     // 4B
  float*  am32   = (float*)(ws + 1024);          // [4096]
  float*  b32    = (float*)(ws + 17408);         // bq|bk|bv|bo  [4][1024]
  float*  zg32   = (float*)(ws + 33792);         // [1024]
  float*  ga32   = (float*)(ws + 37888);         // [1]
  __bf16* MgT16  = (__bf16*)(ws + 38912);        // [16][64][64] M^T, ends 169984
  __bf16* rel16  = (__bf16*)(ws + 301056);       // [131136], ends 563328
  __bf16* hs_pr  = (__bf16*)(ws + 565248);       // [2048][1024] per pair, ends 4759552
  __bf16* WT16   = (__bf16*)(ws + 4759552);      // 4x Wt [n][k], ends 13148160
  __bf16* qkv2   = (__bf16*)(ws + 13148160);     // [2048][3072], ends 25731072
  __bf16* comb2  = (__bf16*)(ws + 25731072);     // [2048][1024], ends 29925376
  __bf16* Vt2    = (__bf16*)(ws + 29925376);     // [2][16][64][1024], ends 34119680

  detect_k<<<1, 256, 0, stream>>>((const uint32_t*)d_in[0], flag);

  cvt_to_f32_k<<<16, 256, 0, stream>>>(d_in[1], am32, 4096, flag);
  const int widx[4] = {2, 4, 6, 8};
  for (int j = 0; j < 4; ++j) {
    cvt_wT_k<<<dim3(32, 32), dim3(32, 8), 0, stream>>>(d_in[widx[j]],
                                                       WT16 + (size_t)j * 1048576, flag);
    cvt_to_f32_k<<<4, 256, 0, stream>>>(d_in[widx[j] + 1], b32 + j * 1024, 1024, flag);
  }
  cvt_to_bf16_k<<<513, 256, 0, stream>>>(d_in[10], 0, rel16, 131136, flag);
  cvt_MgT_k<<<256, 256, 0, stream>>>(d_in[11], MgT16, flag);
  cvt_to_f32_k<<<4, 256, 0, stream>>>(d_in[12], zg32, 1024, flag);
  cvt_to_f32_k<<<1, 256, 0, stream>>>(d_in[13], ga32, 1, flag);

  for (int pr = 0; pr < 2; ++pr) {
    cvt_to_bf16_k<<<8192, 256, 0, stream>>>(d_in[0], (size_t)pr * 2097152, hs_pr,
                                            2097152, flag);
    gemm_bt_k<<<dim3(16, 24), 256, 0, stream>>>(hs_pr, WT16, b32, qkv2,
                                                2048, 3072, 1024, 3072);
    vt2_k<<<dim3(16, 16, 2), 256, 0, stream>>>(qkv2, Vt2);
    attn_fused_k<<<dim3(16, 32), 256, 0, stream>>>(
        qkv2, Vt2, am32 + pr * 2048, rel16, MgT16, zg32, ga32, comb2);
    gemm_bt_out_k<<<dim3(16, 8), 256, 0, stream>>>(
        comb2, WT16 + 3 * 1048576, b32 + 3072, d_out, 2048, 1024, 1024,
        pr * 2048, flag);
  }
}

// Round 27
// 273.129 us; speedup vs baseline: 1.0290x; 1.0290x over previous
//
#include <hip/hip_runtime.h>
#include <cstdint>
#include <cstddef>

typedef __bf16 bf16x8 __attribute__((ext_vector_type(8)));
typedef float f32x4 __attribute__((ext_vector_type(4)));

static __device__ __forceinline__ f32x4 mfma16(bf16x8 a, bf16x8 b, f32x4 c) {
  return __builtin_amdgcn_mfma_f32_16x16x32_bf16(a, b, c, 0, 0, 0);
}

// LAW (R19/R20 proven): compute kernels must NEVER vector-load from d_in —
// d_in is only touched by scalar-load kernels; all bf16x8 loads hit ws.

// ---------------- input dtype sniffing (proven) ----------------
__global__ __launch_bounds__(256) void detect_k(const uint32_t* __restrict__ hs,
                                                int* __restrict__ flag) {
  __shared__ int cnt;
  if (threadIdx.x == 0) cnt = 0;
  __syncthreads();
  uint32_t w = hs[threadIdx.x];
  int b = (w >> 8) & 0x7F;
  if (b >= 0x3C && b <= 0x40) atomicAdd(&cnt, 1);
  __syncthreads();
  if (threadIdx.x == 0) *flag = (cnt >= 128) ? 1 : 0;
}

// ---------------- dtype-adaptive converters (proven; SCALAR d_in reads) ----------
__global__ __launch_bounds__(256) void cvt_to_bf16_k(const void* __restrict__ src,
                                                     size_t srcOff,
                                                     __bf16* __restrict__ dst, int n,
                                                     const int* __restrict__ flag) {
  int i = blockIdx.x * 256 + threadIdx.x;
  if (i >= n) return;
  float v = (*flag) ? (float)((const __bf16*)src)[srcOff + i]
                    : ((const float*)src)[srcOff + i];
  dst[i] = (__bf16)v;
}

__global__ __launch_bounds__(256) void cvt_to_f32_k(const void* __restrict__ src,
                                                    float* __restrict__ dst, int n,
                                                    const int* __restrict__ flag) {
  int i = blockIdx.x * 256 + threadIdx.x;
  if (i >= n) return;
  dst[i] = (*flag) ? (float)((const __bf16*)src)[i] : ((const float*)src)[i];
}

// MgT[h][e][d] = M[h][d][e]
__global__ __launch_bounds__(256) void cvt_MgT_k(const void* __restrict__ src,
                                                 __bf16* __restrict__ dst,
                                                 const int* __restrict__ flag) {
  int i = blockIdx.x * 256 + threadIdx.x;
  if (i >= 65536) return;
  int h = i >> 12, rem = i & 4095, e = rem >> 6, d = rem & 63;
  size_t sidx = (size_t)h * 4096 + d * 64 + e;
  float v = (*flag) ? (float)((const __bf16*)src)[sidx] : ((const float*)src)[sidx];
  dst[i] = (__bf16)v;
}

// Transposing weight converter (R24-proven): W -> Wt[n][k] in ws.
__global__ void cvt_wT_k(const void* __restrict__ W, __bf16* __restrict__ T,
                         const int* __restrict__ flag) {
  __shared__ __bf16 t[32][33];
  int k0 = blockIdx.x * 32, n0 = blockIdx.y * 32;
  int tx = threadIdx.x, ty = threadIdx.y;
  int f = *flag;
#pragma unroll
  for (int i = 0; i < 32; i += 8) {
    size_t idx = (size_t)(k0 + ty + i) * 1024 + n0 + tx;
    float v = f ? (float)((const __bf16*)W)[idx] : ((const float*)W)[idx];
    t[ty + i][tx] = (__bf16)v;
  }
  __syncthreads();
#pragma unroll
  for (int i = 0; i < 32; i += 8)
    T[(size_t)(n0 + ty + i) * 1024 + k0 + tx] = t[tx][ty + i];
}

// ---------------- V transpose to global (R25-proven) ----------------
__global__ __launch_bounds__(256) void vt2_k(const __bf16* __restrict__ qkv2,
                                             __bf16* __restrict__ Vt2) {
  __shared__ __bf16 t[64][72];
  const int h = blockIdx.x, k0 = blockIdx.y * 64, bl = blockIdx.z;
  const int tid = threadIdx.x;
  const int r = tid >> 2, dc = (tid & 3) * 16;
  const __bf16* src = qkv2 + (size_t)(bl * 1024 + k0 + r) * 3072 + 2048 + h * 64 + dc;
  *(bf16x8*)(&t[r][dc]) = *(const bf16x8*)(src);
  *(bf16x8*)(&t[r][dc + 8]) = *(const bf16x8*)(src + 8);
  __syncthreads();
  const int dr = tid >> 2, kc = (tid & 3) * 16;
  __bf16* dst = Vt2 + ((size_t)(bl * 16 + h) * 64 + dr) * 1024 + k0 + kc;
  bf16x8 o0, o1;
#pragma unroll
  for (int j = 0; j < 8; ++j) { o0[j] = t[kc + j][dr]; o1[j] = t[kc + 8 + j][dr]; }
  *(bf16x8*)dst = o0;
  *(bf16x8*)(dst + 8) = o1;
}

// ---------------- m92 XOR-swizzled GEMM (R24-proven) ----------------
__global__ __launch_bounds__(256) void gemm_bt_k(const __bf16* __restrict__ A,
                                                 const __bf16* __restrict__ Bt,
                                                 const float* __restrict__ bias,
                                                 __bf16* __restrict__ C,
                                                 int M, int N, int K, int ldc) {
  const int tm = blockIdx.x * 128, tn = blockIdx.y * 128;
  const int tid = threadIdx.x;
  const int w = tid >> 6, l = tid & 63;
  const int l15 = l & 15, l4 = l >> 4;
  const int wm = (w >> 1) * 64, wn = (w & 1) * 64;
  __shared__ __bf16 As[128 * 64];
  __shared__ __bf16 Bs[128 * 64];
  f32x4 acc[4][4] = {};
  for (int kt = 0; kt < K; kt += 64) {
    __syncthreads();
#pragma unroll
    for (int i = 0; i < 4; ++i) {
      int c = tid + i * 256;
      int r = c >> 3, s = c & 7;
      int byt = r * 128 + ((s ^ (r & 7)) << 4);
      *(bf16x8*)((char*)As + byt) = *(const bf16x8*)(A + (size_t)(tm + r) * K + kt + s * 8);
      *(bf16x8*)((char*)Bs + byt) = *(const bf16x8*)(Bt + (size_t)(tn + r) * K + kt + s * 8);
    }
    __syncthreads();
#pragma unroll
    for (int kk = 0; kk < 2; ++kk) {
      bf16x8 af[4], bfr[4];
#pragma unroll
      for (int m = 0; m < 4; ++m) {
        int row = wm + m * 16 + l15;
        af[m] = *(const bf16x8*)((char*)As + row * 128 + (((l4 + 4 * kk) ^ (row & 7)) << 4));
      }
#pragma unroll
      for (int n = 0; n < 4; ++n) {
        int row = wn + n * 16 + l15;
        bfr[n] = *(const bf16x8*)((char*)Bs + row * 128 + (((l4 + 4 * kk) ^ (row & 7)) << 4));
      }
#pragma unroll
      for (int m = 0; m < 4; ++m)
#pragma unroll
        for (int n = 0; n < 4; ++n)
          acc[m][n] = mfma16(af[m], bfr[n], acc[m][n]);
    }
  }
#pragma unroll
  for (int m = 0; m < 4; ++m)
#pragma unroll
    for (int n = 0; n < 4; ++n) {
      int row = tm + wm + m * 16 + l4 * 4;
      int col = tn + wn + n * 16 + l15;
      float bb = bias[col];
#pragma unroll
      for (int r = 0; r < 4; ++r)
        C[(size_t)(row + r) * ldc + col] = (__bf16)(acc[m][n][r] + bb);
    }
}

__global__ __launch_bounds__(256) void gemm_bt_out_k(const __bf16* __restrict__ A,
                                                     const __bf16* __restrict__ Bt,
                                                     const float* __restrict__ bias,
                                                     void* __restrict__ out,
                                                     int M, int N, int K, int pairOff,
                                                     const int* __restrict__ flag) {
  const int tm = blockIdx.x * 128, tn = blockIdx.y * 128;
  const int tid = threadIdx.x;
  const int w = tid >> 6, l = tid & 63;
  const int l15 = l & 15, l4 = l >> 4;
  const int wm = (w >> 1) * 64, wn = (w & 1) * 64;
  __shared__ __bf16 As[128 * 64];
  __shared__ __bf16 Bs[128 * 64];
  f32x4 acc[4][4] = {};
  for (int kt = 0; kt < K; kt += 64) {
    __syncthreads();
#pragma unroll
    for (int i = 0; i < 4; ++i) {
      int c = tid + i * 256;
      int r = c >> 3, s = c & 7;
      int byt = r * 128 + ((s ^ (r & 7)) << 4);
      *(bf16x8*)((char*)As + byt) = *(const bf16x8*)(A + (size_t)(tm + r) * K + kt + s * 8);
      *(bf16x8*)((char*)Bs + byt) = *(const bf16x8*)(Bt + (size_t)(tn + r) * K + kt + s * 8);
    }
    __syncthreads();
#pragma unroll
    for (int kk = 0; kk < 2; ++kk) {
      bf16x8 af[4], bfr[4];
#pragma unroll
      for (int m = 0; m < 4; ++m) {
        int row = wm + m * 16 + l15;
        af[m] = *(const bf16x8*)((char*)As + row * 128 + (((l4 + 4 * kk) ^ (row & 7)) << 4));
      }
#pragma unroll
      for (int n = 0; n < 4; ++n) {
        int row = wn + n * 16 + l15;
        bfr[n] = *(const bf16x8*)((char*)Bs + row * 128 + (((l4 + 4 * kk) ^ (row & 7)) << 4));
      }
#pragma unroll
      for (int m = 0; m < 4; ++m)
#pragma unroll
        for (int n = 0; n < 4; ++n)
          acc[m][n] = mfma16(af[m], bfr[n], acc[m][n]);
    }
  }
  int use16 = *flag;
#pragma unroll
  for (int m = 0; m < 4; ++m)
#pragma unroll
    for (int n = 0; n < 4; ++n) {
      int row = tm + wm + m * 16 + l4 * 4;
      int col = tn + wn + n * 16 + l15;
      float bb = bias[col];
#pragma unroll
      for (int r = 0; r < 4; ++r) {
        float v = acc[m][n][r] + bb;
        size_t idx = (size_t)(pairOff + row + r) * N + col;
        if (use16) ((__bf16*)out)[idx] = (__bf16)v;
        else       ((float*)out)[idx] = v;
      }
    }
}

// ---------------- MFMA fused attention: R25 layout + T14 async-STAGE split --------
// K/V/mask for tile kt+1 loaded to REGS during tile kt's compute; ds_write next iter.
__global__ __launch_bounds__(256) void attn_fused_k(const __bf16* __restrict__ QKV2,
                                                    const __bf16* __restrict__ Vt2,
                                                    const float* __restrict__ amask,
                                                    const __bf16* __restrict__ rel16,
                                                    const __bf16* __restrict__ MgT16,
                                                    const float* __restrict__ zg32,
                                                    const float* __restrict__ ga32,
                                                    __bf16* __restrict__ comb) {
  const int qt = blockIdx.x, bh = blockIdx.y;
  const int bl = bh >> 4, h = bh & 15;
  const int tid = threadIdx.x;
  const int w = tid >> 6, l = tid & 63;
  const int l15 = l & 15, l4 = l >> 4;
  const int q0 = qt * 64;
  const __bf16* QKVb = QKV2 + (size_t)bl * 1024 * 3072;
  const __bf16* VtH = Vt2 + (size_t)(bl * 16 + h) * 64 * 1024;

  __shared__ __bf16 Kt[64][72];
  __shared__ __bf16 VtT[64][72];
  __shared__ __bf16 Pl[4][16 * 72];
  __shared__ float RKb[128 * 66];
  __shared__ float maskv[64];
  __shared__ float denv[64];

  bf16x8 qf[2];
#pragma unroll
  for (int kk = 0; kk < 2; ++kk)
    qf[kk] = *(const bf16x8*)(QKVb + (size_t)(q0 + w * 16 + l15) * 3072 + h * 64 +
                              l4 * 8 + kk * 32);

  // staging-lane geometry (i = 0,1): c = tid + i*256 -> (kr, s)
  const int kr0 = tid >> 3, s0 = (tid & 7) * 8;
  const int kr1 = (tid + 256) >> 3, s1 = ((tid + 256) & 7) * 8;

  f32x4 accO[4] = {};
  float mrun[4], lrun[4];
#pragma unroll
  for (int r = 0; r < 4; ++r) { mrun[r] = -3.0e38f; lrun[r] = 0.f; }

  // prologue: load tile 0 into regs
  bf16x8 kreg0, kreg1, vreg0, vreg1;
  float mreg = 0.f;
  kreg0 = *(const bf16x8*)(QKVb + (size_t)kr0 * 3072 + 1024 + h * 64 + s0);
  kreg1 = *(const bf16x8*)(QKVb + (size_t)kr1 * 3072 + 1024 + h * 64 + s1);
  vreg0 = *(const bf16x8*)(VtH + (size_t)kr0 * 1024 + s0);
  vreg1 = *(const bf16x8*)(VtH + (size_t)kr1 * 1024 + s1);
  if (tid < 64) mreg = amask[bl * 1024 + tid];

  for (int kt = 0; kt < 16; ++kt) {
    const int k0 = kt * 64;
    __syncthreads();   // previous tile's LDS consumers done
    *(bf16x8*)(&Kt[kr0][s0]) = kreg0;
    *(bf16x8*)(&Kt[kr1][s1]) = kreg1;
    *(bf16x8*)(&VtT[kr0][s0]) = vreg0;
    *(bf16x8*)(&VtT[kr1][s1]) = vreg1;
    if (tid < 64) maskv[tid] = mreg;
    __syncthreads();

    // T14: issue next tile's loads now; latency hides under compute below
    if (kt < 15) {
      const int kn = k0 + 64;
      kreg0 = *(const bf16x8*)(QKVb + (size_t)(kn + kr0) * 3072 + 1024 + h * 64 + s0);
      kreg1 = *(const bf16x8*)(QKVb + (size_t)(kn + kr1) * 3072 + 1024 + h * 64 + s1);
      vreg0 = *(const bf16x8*)(VtH + (size_t)kr0 * 1024 + kn + s0);
      vreg1 = *(const bf16x8*)(VtH + (size_t)kr1 * 1024 + kn + s1);
      if (tid < 64) mreg = amask[bl * 1024 + kn + tid];
    }

    const int jb = q0 - k0 - 63 + 1024;
#pragma unroll
    for (int ms = 0; ms < 2; ++ms) {
      f32x4 rk[4] = {};
#pragma unroll
      for (int kk = 0; kk < 2; ++kk) {
        bf16x8 ea = *(const bf16x8*)(rel16 + (size_t)(jb + w * 32 + ms * 16 + l15) * 64 +
                                     l4 * 8 + kk * 32);
#pragma unroll
        for (int nb = 0; nb < 4; ++nb) {
          bf16x8 kb = *(const bf16x8*)(&Kt[nb * 16 + l15][l4 * 8 + kk * 32]);
          rk[nb] = mfma16(ea, kb, rk[nb]);
        }
      }
#pragma unroll
      for (int nb = 0; nb < 4; ++nb)
#pragma unroll
        for (int r = 0; r < 4; ++r)
          RKb[(w * 32 + ms * 16 + l4 * 4 + r) * 66 + nb * 16 + l15] = rk[nb][r];
    }
    __syncthreads();

    f32x4 sacc[4] = {};
#pragma unroll
    for (int kk = 0; kk < 2; ++kk)
#pragma unroll
      for (int nb = 0; nb < 4; ++nb) {
        bf16x8 kb = *(const bf16x8*)(&Kt[nb * 16 + l15][l4 * 8 + kk * 32]);
        sacc[nb] = mfma16(qf[kk], kb, sacc[nb]);
      }

    float p[4][4];
    float tmax[4];
#pragma unroll
    for (int r = 0; r < 4; ++r) tmax[r] = -3.0e38f;
#pragma unroll
    for (int nb = 0; nb < 4; ++nb) {
      int kloc = nb * 16 + l15;
      float mk = maskv[kloc] * (-1e9f);
#pragma unroll
      for (int r = 0; r < 4; ++r) {
        int jl = (w * 16 + l4 * 4 + r) - kloc + 63;
        float s = (sacc[nb][r] + RKb[jl * 66 + kloc]) * 0.125f + mk;
        p[nb][r] = s;
        tmax[r] = fmaxf(tmax[r], s);
      }
    }
#pragma unroll
    for (int x = 1; x < 16; x <<= 1)
#pragma unroll
      for (int r = 0; r < 4; ++r) tmax[r] = fmaxf(tmax[r], __shfl_xor(tmax[r], x, 64));
    float al[4];
#pragma unroll
    for (int r = 0; r < 4; ++r) {
      float mn = fmaxf(mrun[r], tmax[r]);
      al[r] = __expf(mrun[r] - mn);
      mrun[r] = mn;
    }
    float rs[4] = {0.f, 0.f, 0.f, 0.f};
#pragma unroll
    for (int nb = 0; nb < 4; ++nb)
#pragma unroll
      for (int r = 0; r < 4; ++r) {
        p[nb][r] = __expf(p[nb][r] - mrun[r]);
        rs[r] += p[nb][r];
      }
#pragma unroll
    for (int x = 1; x < 16; x <<= 1)
#pragma unroll
      for (int r = 0; r < 4; ++r) rs[r] += __shfl_xor(rs[r], x, 64);
#pragma unroll
    for (int r = 0; r < 4; ++r) lrun[r] = lrun[r] * al[r] + rs[r];
#pragma unroll
    for (int nb = 0; nb < 4; ++nb)
#pragma unroll
      for (int r = 0; r < 4; ++r) accO[nb][r] *= al[r];

#pragma unroll
    for (int nb = 0; nb < 4; ++nb)
#pragma unroll
      for (int r = 0; r < 4; ++r)
        Pl[w][(l4 * 4 + r) * 72 + nb * 16 + l15] = (__bf16)p[nb][r];
    __syncthreads();

#pragma unroll
    for (int kk = 0; kk < 2; ++kk) {
      bf16x8 pa = *(const bf16x8*)(&Pl[w][l15 * 72 + kk * 32 + l4 * 8]);
#pragma unroll
      for (int nb = 0; nb < 4; ++nb) {
        bf16x8 vb = *(const bf16x8*)(&VtT[nb * 16 + l15][kk * 32 + l4 * 8]);
        accO[nb] = mfma16(pa, vb, accO[nb]);
      }
    }
  }

#pragma unroll
  for (int nb = 0; nb < 4; ++nb)
#pragma unroll
    for (int r = 0; r < 4; ++r) accO[nb][r] /= lrun[r];

  // ---- epilogue (overlays RKb); Mtb staged vector from MgT16 ----
  __syncthreads();
  __bf16* sqb = (__bf16*)RKb;
  __bf16* Mtb = ((__bf16*)RKb) + 64 * 72;
#pragma unroll
  for (int i = 0; i < 2; ++i) {
    int c = tid + i * 256;
    int qr = c >> 3, s = (c & 7) * 8;
    bf16x8 qv = *(const bf16x8*)(QKVb + (size_t)(q0 + qr) * 3072 + h * 64 + s);
#pragma unroll
    for (int j = 0; j < 8; ++j) {
      float x = (float)qv[j];
      sqb[qr * 72 + s + j] = (__bf16)(x > 0.f ? x + 1.f : __expf(x));
    }
    bf16x8 mv = *(const bf16x8*)(MgT16 + (size_t)h * 4096 + qr * 64 + s);
    *(bf16x8*)(&Mtb[qr * 72 + s]) = mv;
  }
  __syncthreads();
  if (tid < 64) {
    float sden = 0.f;
    const float* zp = zg32 + h * 64;
#pragma unroll
    for (int d = 0; d < 64; ++d) sden += (float)sqb[tid * 72 + d] * zp[d];
    denv[tid] = sden + 1e-6f;
  }
  __syncthreads();
  float gate = 1.f / (1.f + __expf(-ga32[0]));
  f32x4 nacc[4] = {};
#pragma unroll
  for (int kk = 0; kk < 2; ++kk) {
    bf16x8 sa = *(const bf16x8*)(sqb + (w * 16 + l15) * 72 + kk * 32 + l4 * 8);
#pragma unroll
    for (int nb = 0; nb < 4; ++nb) {
      bf16x8 mb = *(const bf16x8*)(Mtb + (nb * 16 + l15) * 72 + kk * 32 + l4 * 8);
      nacc[nb] = mfma16(sa, mb, nacc[nb]);
    }
  }
#pragma unroll
  for (int nb = 0; nb < 4; ++nb)
#pragma unroll
    for (int r = 0; r < 4; ++r) {
      int qrel = w * 16 + l4 * 4 + r;
      float gl = nacc[nb][r] / denv[qrel];
      float cv = gate * accO[nb][r] + (1.f - gate) * gl;
      comb[(size_t)(bl * 1024 + q0 + qrel) * 1024 + h * 64 + nb * 16 + l15] = (__bf16)cv;
    }
}

// ---------------- launcher ----------------
extern "C" void kernel_launch(void* const* d_in, const int* in_sizes, int n_in,
                              void* d_out, int out_size, void* d_ws, size_t ws_size,
                              hipStream_t stream) {
  const int expect[14] = {4194304, 4096, 1048576, 1024, 1048576, 1024, 1048576,
                          1024, 1048576, 1024, 131136, 65536, 1024, 1};
  if (n_in != 14) return;
  for (int i = 0; i < 14; ++i)
    if (in_sizes[i] != expect[i]) return;

  char* ws = (char*)d_ws;
  int*    flag   = (int*)ws;                     // 4B
  float*  am32   = (float*)(ws + 1024);          // [4096]
  float*  b32    = (float*)(ws + 17408);         // bq|bk|bv|bo  [4][1024]
  float*  zg32   = (float*)(ws + 33792);         // [1024]
  float*  ga32   = (float*)(ws + 37888);         // [1]
  __bf16* MgT16  = (__bf16*)(ws + 38912);        // [16][64][64] M^T, ends 169984
  __bf16* rel16  = (__bf16*)(ws + 301056);       // [131136], ends 563328
  __bf16* hs_pr  = (__bf16*)(ws + 565248);       // [2048][1024] per pair, ends 4759552
  __bf16* WT16   = (__bf16*)(ws + 4759552);      // 4x Wt [n][k], ends 13148160
  __bf16* qkv2   = (__bf16*)(ws + 13148160);     // [2048][3072], ends 25731072
  __bf16* comb2  = (__bf16*)(ws + 25731072);     // [2048][1024], ends 29925376
  __bf16* Vt2    = (__bf16*)(ws + 29925376);     // [2][16][64][1024], ends 34119680

  detect_k<<<1, 256, 0, stream>>>((const uint32_t*)d_in[0], flag);

  cvt_to_f32_k<<<16, 256, 0, stream>>>(d_in[1], am32, 4096, flag);
  const int widx[4] = {2, 4, 6, 8};
  for (int j = 0; j < 4; ++j) {
    cvt_wT_k<<<dim3(32, 32), dim3(32, 8), 0, stream>>>(d_in[widx[j]],
                                                       WT16 + (size_t)j * 1048576, flag);
    cvt_to_f32_k<<<4, 256, 0, stream>>>(d_in[widx[j] + 1], b32 + j * 1024, 1024, flag);
  }
  cvt_to_bf16_k<<<513, 256, 0, stream>>>(d_in[10], 0, rel16, 131136, flag);
  cvt_MgT_k<<<256, 256, 0, stream>>>(d_in[11], MgT16, flag);
  cvt_to_f32_k<<<4, 256, 0, stream>>>(d_in[12], zg32, 1024, flag);
  cvt_to_f32_k<<<1, 256, 0, stream>>>(d_in[13], ga32, 1, flag);

  for (int pr = 0; pr < 2; ++pr) {
    cvt_to_bf16_k<<<8192, 256, 0, stream>>>(d_in[0], (size_t)pr * 2097152, hs_pr,
                                            2097152, flag);
    gemm_bt_k<<<dim3(16, 24), 256, 0, stream>>>(hs_pr, WT16, b32, qkv2,
                                                2048, 3072, 1024, 3072);
    vt2_k<<<dim3(16, 16, 2), 256, 0, stream>>>(qkv2, Vt2);
    attn_fused_k<<<dim3(16, 32), 256, 0, stream>>>(
        qkv2, Vt2, am32 + pr * 2048, rel16, MgT16, zg32, ga32, comb2);
    gemm_bt_out_k<<<dim3(16, 8), 256, 0, stream>>>(
        comb2, WT16 + 3 * 1048576, b32 + 3072, d_out, 2048, 1024, 1024,
        pr * 2048, flag);
  }
}

// Round 28
// 257.019 us; speedup vs baseline: 1.0935x; 1.0627x over previous
//
#include <hip/hip_runtime.h>
#include <cstdint>
#include <cstddef>

typedef __bf16 bf16x8 __attribute__((ext_vector_type(8)));
typedef float f32x4 __attribute__((ext_vector_type(4)));

static __device__ __forceinline__ f32x4 mfma16(bf16x8 a, bf16x8 b, f32x4 c) {
  return __builtin_amdgcn_mfma_f32_16x16x32_bf16(a, b, c, 0, 0, 0);
}

// LAW (R19/R20 proven): compute kernels must NEVER vector-load from d_in —
// d_in is only touched by scalar-load kernels; all bf16x8 loads hit ws.

// ---------------- input dtype sniffing (proven) ----------------
__global__ __launch_bounds__(256) void detect_k(const uint32_t* __restrict__ hs,
                                                int* __restrict__ flag) {
  __shared__ int cnt;
  if (threadIdx.x == 0) cnt = 0;
  __syncthreads();
  uint32_t w = hs[threadIdx.x];
  int b = (w >> 8) & 0x7F;
  if (b >= 0x3C && b <= 0x40) atomicAdd(&cnt, 1);
  __syncthreads();
  if (threadIdx.x == 0) *flag = (cnt >= 128) ? 1 : 0;
}

static __device__ __forceinline__ float ld_in(const void* p, size_t i, int f) {
  return f ? (float)((const __bf16*)p)[i] : ((const float*)p)[i];
}

// ---------------- merged small-tensor converter (single launch) ----------------
// blocks [0,16): amask->f32; [16,32): biases(4x1024)->f32; [32,36): zg->f32;
// block 36: ga; [37,550): rel16; [550,806): MgT16.
__global__ __launch_bounds__(256) void mono_cvt_k(const void* __restrict__ amask,
                                                  const void* __restrict__ bq,
                                                  const void* __restrict__ bk,
                                                  const void* __restrict__ bv,
                                                  const void* __restrict__ bo,
                                                  const void* __restrict__ zg,
                                                  const void* __restrict__ ga,
                                                  const void* __restrict__ rel,
                                                  const void* __restrict__ Mg,
                                                  float* __restrict__ am32,
                                                  float* __restrict__ b32,
                                                  float* __restrict__ zg32,
                                                  float* __restrict__ ga32,
                                                  __bf16* __restrict__ rel16,
                                                  __bf16* __restrict__ MgT16,
                                                  const int* __restrict__ flag) {
  const int f = *flag;
  const int b = blockIdx.x, t = threadIdx.x;
  if (b < 16) {
    int i = b * 256 + t;
    am32[i] = ld_in(amask, i, f);
  } else if (b < 32) {
    int i = (b - 16) * 256 + t;          // 4096 = 4 x 1024
    const void* src = (i < 1024) ? bq : (i < 2048) ? bk : (i < 3072) ? bv : bo;
    b32[i] = ld_in(src, i & 1023, f);
  } else if (b < 36) {
    int i = (b - 32) * 256 + t;
    zg32[i] = ld_in(zg, i, f);
  } else if (b == 36) {
    if (t == 0) ga32[0] = ld_in(ga, 0, f);
  } else if (b < 550) {
    int i = (b - 37) * 256 + t;
    if (i < 131136) rel16[i] = (__bf16)ld_in(rel, i, f);
  } else {
    int i = (b - 550) * 256 + t;         // 65536 MgT
    if (i < 65536) {
      int h = i >> 12, rem = i & 4095, e = rem >> 6, d = rem & 63;
      MgT16[i] = (__bf16)ld_in(Mg, (size_t)h * 4096 + d * 64 + e, f);
    }
  }
}

// hs pair converter (scalar d_in reads)
__global__ __launch_bounds__(256) void cvt_hs_k(const void* __restrict__ src,
                                                size_t srcOff,
                                                __bf16* __restrict__ dst, int n,
                                                const int* __restrict__ flag) {
  int i = blockIdx.x * 256 + threadIdx.x;
  if (i >= n) return;
  dst[i] = (__bf16)ld_in(src, srcOff + i, *flag);
}

// Transposing weight converter (R24-proven): W -> Wt[n][k] in ws.
__global__ void cvt_wT_k(const void* __restrict__ W, __bf16* __restrict__ T,
                         const int* __restrict__ flag) {
  __shared__ __bf16 t[32][33];
  int k0 = blockIdx.x * 32, n0 = blockIdx.y * 32;
  int tx = threadIdx.x, ty = threadIdx.y;
  int f = *flag;
#pragma unroll
  for (int i = 0; i < 32; i += 8)
    t[ty + i][tx] = (__bf16)ld_in(W, (size_t)(k0 + ty + i) * 1024 + n0 + tx, f);
  __syncthreads();
#pragma unroll
  for (int i = 0; i < 32; i += 8)
    T[(size_t)(n0 + ty + i) * 1024 + k0 + tx] = t[tx][ty + i];
}

// ---------------- V transpose to global (R25-proven) ----------------
__global__ __launch_bounds__(256) void vt2_k(const __bf16* __restrict__ qkv2,
                                             __bf16* __restrict__ Vt2) {
  __shared__ __bf16 t[64][72];
  const int h = blockIdx.x, k0 = blockIdx.y * 64, bl = blockIdx.z;
  const int tid = threadIdx.x;
  const int r = tid >> 2, dc = (tid & 3) * 16;
  const __bf16* src = qkv2 + (size_t)(bl * 1024 + k0 + r) * 3072 + 2048 + h * 64 + dc;
  *(bf16x8*)(&t[r][dc]) = *(const bf16x8*)(src);
  *(bf16x8*)(&t[r][dc + 8]) = *(const bf16x8*)(src + 8);
  __syncthreads();
  const int dr = tid >> 2, kc = (tid & 3) * 16;
  __bf16* dst = Vt2 + ((size_t)(bl * 16 + h) * 64 + dr) * 1024 + k0 + kc;
  bf16x8 o0, o1;
#pragma unroll
  for (int j = 0; j < 8; ++j) { o0[j] = t[kc + j][dr]; o1[j] = t[kc + 8 + j][dr]; }
  *(bf16x8*)dst = o0;
  *(bf16x8*)(dst + 8) = o1;
}

// ---------------- m92 XOR-swizzled GEMM (R24-proven) ----------------
__global__ __launch_bounds__(256) void gemm_bt_k(const __bf16* __restrict__ A,
                                                 const __bf16* __restrict__ Bt,
                                                 const float* __restrict__ bias,
                                                 __bf16* __restrict__ C,
                                                 int M, int N, int K, int ldc) {
  const int tm = blockIdx.x * 128, tn = blockIdx.y * 128;
  const int tid = threadIdx.x;
  const int w = tid >> 6, l = tid & 63;
  const int l15 = l & 15, l4 = l >> 4;
  const int wm = (w >> 1) * 64, wn = (w & 1) * 64;
  __shared__ __bf16 As[128 * 64];
  __shared__ __bf16 Bs[128 * 64];
  f32x4 acc[4][4] = {};
  for (int kt = 0; kt < K; kt += 64) {
    __syncthreads();
#pragma unroll
    for (int i = 0; i < 4; ++i) {
      int c = tid + i * 256;
      int r = c >> 3, s = c & 7;
      int byt = r * 128 + ((s ^ (r & 7)) << 4);
      *(bf16x8*)((char*)As + byt) = *(const bf16x8*)(A + (size_t)(tm + r) * K + kt + s * 8);
      *(bf16x8*)((char*)Bs + byt) = *(const bf16x8*)(Bt + (size_t)(tn + r) * K + kt + s * 8);
    }
    __syncthreads();
#pragma unroll
    for (int kk = 0; kk < 2; ++kk) {
      bf16x8 af[4], bfr[4];
#pragma unroll
      for (int m = 0; m < 4; ++m) {
        int row = wm + m * 16 + l15;
        af[m] = *(const bf16x8*)((char*)As + row * 128 + (((l4 + 4 * kk) ^ (row & 7)) << 4));
      }
#pragma unroll
      for (int n = 0; n < 4; ++n) {
        int row = wn + n * 16 + l15;
        bfr[n] = *(const bf16x8*)((char*)Bs + row * 128 + (((l4 + 4 * kk) ^ (row & 7)) << 4));
      }
#pragma unroll
      for (int m = 0; m < 4; ++m)
#pragma unroll
        for (int n = 0; n < 4; ++n)
          acc[m][n] = mfma16(af[m], bfr[n], acc[m][n]);
    }
  }
#pragma unroll
  for (int m = 0; m < 4; ++m)
#pragma unroll
    for (int n = 0; n < 4; ++n) {
      int row = tm + wm + m * 16 + l4 * 4;
      int col = tn + wn + n * 16 + l15;
      float bb = bias[col];
#pragma unroll
      for (int r = 0; r < 4; ++r)
        C[(size_t)(row + r) * ldc + col] = (__bf16)(acc[m][n][r] + bb);
    }
}

__global__ __launch_bounds__(256) void gemm_bt_out_k(const __bf16* __restrict__ A,
                                                     const __bf16* __restrict__ Bt,
                                                     const float* __restrict__ bias,
                                                     void* __restrict__ out,
                                                     int M, int N, int K, int pairOff,
                                                     const int* __restrict__ flag) {
  const int tm = blockIdx.x * 128, tn = blockIdx.y * 128;
  const int tid = threadIdx.x;
  const int w = tid >> 6, l = tid & 63;
  const int l15 = l & 15, l4 = l >> 4;
  const int wm = (w >> 1) * 64, wn = (w & 1) * 64;
  __shared__ __bf16 As[128 * 64];
  __shared__ __bf16 Bs[128 * 64];
  f32x4 acc[4][4] = {};
  for (int kt = 0; kt < K; kt += 64) {
    __syncthreads();
#pragma unroll
    for (int i = 0; i < 4; ++i) {
      int c = tid + i * 256;
      int r = c >> 3, s = c & 7;
      int byt = r * 128 + ((s ^ (r & 7)) << 4);
      *(bf16x8*)((char*)As + byt) = *(const bf16x8*)(A + (size_t)(tm + r) * K + kt + s * 8);
      *(bf16x8*)((char*)Bs + byt) = *(const bf16x8*)(Bt + (size_t)(tn + r) * K + kt + s * 8);
    }
    __syncthreads();
#pragma unroll
    for (int kk = 0; kk < 2; ++kk) {
      bf16x8 af[4], bfr[4];
#pragma unroll
      for (int m = 0; m < 4; ++m) {
        int row = wm + m * 16 + l15;
        af[m] = *(const bf16x8*)((char*)As + row * 128 + (((l4 + 4 * kk) ^ (row & 7)) << 4));
      }
#pragma unroll
      for (int n = 0; n < 4; ++n) {
        int row = wn + n * 16 + l15;
        bfr[n] = *(const bf16x8*)((char*)Bs + row * 128 + (((l4 + 4 * kk) ^ (row & 7)) << 4));
      }
#pragma unroll
      for (int m = 0; m < 4; ++m)
#pragma unroll
        for (int n = 0; n < 4; ++n)
          acc[m][n] = mfma16(af[m], bfr[n], acc[m][n]);
    }
  }
  int use16 = *flag;
#pragma unroll
  for (int m = 0; m < 4; ++m)
#pragma unroll
    for (int n = 0; n < 4; ++n) {
      int row = tm + wm + m * 16 + l4 * 4;
      int col = tn + wn + n * 16 + l15;
      float bb = bias[col];
#pragma unroll
      for (int r = 0; r < 4; ++r) {
        float v = acc[m][n][r] + bb;
        size_t idx = (size_t)(pairOff + row + r) * N + col;
        if (use16) ((__bf16*)out)[idx] = (__bf16)v;
        else       ((float*)out)[idx] = v;
      }
    }
}

// ---------------- MFMA fused attention (R25-exact, best measured 66.4 us) ----------
__global__ __launch_bounds__(256) void attn_fused_k(const __bf16* __restrict__ QKV2,
                                                    const __bf16* __restrict__ Vt2,
                                                    const float* __restrict__ amask,
                                                    const __bf16* __restrict__ rel16,
                                                    const __bf16* __restrict__ MgT16,
                                                    const float* __restrict__ zg32,
                                                    const float* __restrict__ ga32,
                                                    __bf16* __restrict__ comb) {
  const int qt = blockIdx.x, bh = blockIdx.y;
  const int bl = bh >> 4, h = bh & 15;
  const int tid = threadIdx.x;
  const int w = tid >> 6, l = tid & 63;
  const int l15 = l & 15, l4 = l >> 4;
  const int q0 = qt * 64;
  const __bf16* QKVb = QKV2 + (size_t)bl * 1024 * 3072;
  const __bf16* VtH = Vt2 + (size_t)(bl * 16 + h) * 64 * 1024;

  __shared__ __bf16 Kt[64][72];
  __shared__ __bf16 VtT[64][72];
  __shared__ __bf16 Pl[4][16 * 72];
  __shared__ float RKb[128 * 66];
  __shared__ float maskv[64];
  __shared__ float denv[64];

  bf16x8 qf[2];
#pragma unroll
  for (int kk = 0; kk < 2; ++kk)
    qf[kk] = *(const bf16x8*)(QKVb + (size_t)(q0 + w * 16 + l15) * 3072 + h * 64 +
                              l4 * 8 + kk * 32);

  f32x4 accO[4] = {};
  float mrun[4], lrun[4];
#pragma unroll
  for (int r = 0; r < 4; ++r) { mrun[r] = -3.0e38f; lrun[r] = 0.f; }

  for (int kt = 0; kt < 16; ++kt) {
    const int k0 = kt * 64;
    __syncthreads();
#pragma unroll
    for (int i = 0; i < 2; ++i) {
      int c = tid + i * 256;
      int kr = c >> 3, s = (c & 7) * 8;
      *(bf16x8*)(&Kt[kr][s]) =
          *(const bf16x8*)(QKVb + (size_t)(k0 + kr) * 3072 + 1024 + h * 64 + s);
      *(bf16x8*)(&VtT[kr][s]) = *(const bf16x8*)(VtH + (size_t)kr * 1024 + k0 + s);
    }
    if (tid < 64) maskv[tid] = amask[bl * 1024 + k0 + tid];
    __syncthreads();

    const int jb = q0 - k0 - 63 + 1024;
#pragma unroll
    for (int ms = 0; ms < 2; ++ms) {
      f32x4 rk[4] = {};
#pragma unroll
      for (int kk = 0; kk < 2; ++kk) {
        bf16x8 ea = *(const bf16x8*)(rel16 + (size_t)(jb + w * 32 + ms * 16 + l15) * 64 +
                                     l4 * 8 + kk * 32);
#pragma unroll
        for (int nb = 0; nb < 4; ++nb) {
          bf16x8 kb = *(const bf16x8*)(&Kt[nb * 16 + l15][l4 * 8 + kk * 32]);
          rk[nb] = mfma16(ea, kb, rk[nb]);
        }
      }
#pragma unroll
      for (int nb = 0; nb < 4; ++nb)
#pragma unroll
        for (int r = 0; r < 4; ++r)
          RKb[(w * 32 + ms * 16 + l4 * 4 + r) * 66 + nb * 16 + l15] = rk[nb][r];
    }
    __syncthreads();

    f32x4 sacc[4] = {};
#pragma unroll
    for (int kk = 0; kk < 2; ++kk)
#pragma unroll
      for (int nb = 0; nb < 4; ++nb) {
        bf16x8 kb = *(const bf16x8*)(&Kt[nb * 16 + l15][l4 * 8 + kk * 32]);
        sacc[nb] = mfma16(qf[kk], kb, sacc[nb]);
      }

    float p[4][4];
    float tmax[4];
#pragma unroll
    for (int r = 0; r < 4; ++r) tmax[r] = -3.0e38f;
#pragma unroll
    for (int nb = 0; nb < 4; ++nb) {
      int kloc = nb * 16 + l15;
      float mk = maskv[kloc] * (-1e9f);
#pragma unroll
      for (int r = 0; r < 4; ++r) {
        int jl = (w * 16 + l4 * 4 + r) - kloc + 63;
        float s = (sacc[nb][r] + RKb[jl * 66 + kloc]) * 0.125f + mk;
        p[nb][r] = s;
        tmax[r] = fmaxf(tmax[r], s);
      }
    }
#pragma unroll
    for (int x = 1; x < 16; x <<= 1)
#pragma unroll
      for (int r = 0; r < 4; ++r) tmax[r] = fmaxf(tmax[r], __shfl_xor(tmax[r], x, 64));
    float al[4];
#pragma unroll
    for (int r = 0; r < 4; ++r) {
      float mn = fmaxf(mrun[r], tmax[r]);
      al[r] = __expf(mrun[r] - mn);
      mrun[r] = mn;
    }
    float rs[4] = {0.f, 0.f, 0.f, 0.f};
#pragma unroll
    for (int nb = 0; nb < 4; ++nb)
#pragma unroll
      for (int r = 0; r < 4; ++r) {
        p[nb][r] = __expf(p[nb][r] - mrun[r]);
        rs[r] += p[nb][r];
      }
#pragma unroll
    for (int x = 1; x < 16; x <<= 1)
#pragma unroll
      for (int r = 0; r < 4; ++r) rs[r] += __shfl_xor(rs[r], x, 64);
#pragma unroll
    for (int r = 0; r < 4; ++r) lrun[r] = lrun[r] * al[r] + rs[r];
#pragma unroll
    for (int nb = 0; nb < 4; ++nb)
#pragma unroll
      for (int r = 0; r < 4; ++r) accO[nb][r] *= al[r];

#pragma unroll
    for (int nb = 0; nb < 4; ++nb)
#pragma unroll
      for (int r = 0; r < 4; ++r)
        Pl[w][(l4 * 4 + r) * 72 + nb * 16 + l15] = (__bf16)p[nb][r];
    __syncthreads();

#pragma unroll
    for (int kk = 0; kk < 2; ++kk) {
      bf16x8 pa = *(const bf16x8*)(&Pl[w][l15 * 72 + kk * 32 + l4 * 8]);
#pragma unroll
      for (int nb = 0; nb < 4; ++nb) {
        bf16x8 vb = *(const bf16x8*)(&VtT[nb * 16 + l15][kk * 32 + l4 * 8]);
        accO[nb] = mfma16(pa, vb, accO[nb]);
      }
    }
  }

#pragma unroll
  for (int nb = 0; nb < 4; ++nb)
#pragma unroll
    for (int r = 0; r < 4; ++r) accO[nb][r] /= lrun[r];

  // ---- epilogue (overlays RKb); Mtb staged vector from MgT16 ----
  __syncthreads();
  __bf16* sqb = (__bf16*)RKb;
  __bf16* Mtb = ((__bf16*)RKb) + 64 * 72;
#pragma unroll
  for (int i = 0; i < 2; ++i) {
    int c = tid + i * 256;
    int qr = c >> 3, s = (c & 7) * 8;
    bf16x8 qv = *(const bf16x8*)(QKVb + (size_t)(q0 + qr) * 3072 + h * 64 + s);
#pragma unroll
    for (int j = 0; j < 8; ++j) {
      float x = (float)qv[j];
      sqb[qr * 72 + s + j] = (__bf16)(x > 0.f ? x + 1.f : __expf(x));
    }
    bf16x8 mv = *(const bf16x8*)(MgT16 + (size_t)h * 4096 + qr * 64 + s);
    *(bf16x8*)(&Mtb[qr * 72 + s]) = mv;
  }
  __syncthreads();
  if (tid < 64) {
    float sden = 0.f;
    const float* zp = zg32 + h * 64;
#pragma unroll
    for (int d = 0; d < 64; ++d) sden += (float)sqb[tid * 72 + d] * zp[d];
    denv[tid] = sden + 1e-6f;
  }
  __syncthreads();
  float gate = 1.f / (1.f + __expf(-ga32[0]));
  f32x4 nacc[4] = {};
#pragma unroll
  for (int kk = 0; kk < 2; ++kk) {
    bf16x8 sa = *(const bf16x8*)(sqb + (w * 16 + l15) * 72 + kk * 32 + l4 * 8);
#pragma unroll
    for (int nb = 0; nb < 4; ++nb) {
      bf16x8 mb = *(const bf16x8*)(Mtb + (nb * 16 + l15) * 72 + kk * 32 + l4 * 8);
      nacc[nb] = mfma16(sa, mb, nacc[nb]);
    }
  }
#pragma unroll
  for (int nb = 0; nb < 4; ++nb)
#pragma unroll
    for (int r = 0; r < 4; ++r) {
      int qrel = w * 16 + l4 * 4 + r;
      float gl = nacc[nb][r] / denv[qrel];
      float cv = gate * accO[nb][r] + (1.f - gate) * gl;
      comb[(size_t)(bl * 1024 + q0 + qrel) * 1024 + h * 64 + nb * 16 + l15] = (__bf16)cv;
    }
}

// ---------------- launcher ----------------
extern "C" void kernel_launch(void* const* d_in, const int* in_sizes, int n_in,
                              void* d_out, int out_size, void* d_ws, size_t ws_size,
                              hipStream_t stream) {
  const int expect[14] = {4194304, 4096, 1048576, 1024, 1048576, 1024, 1048576,
                          1024, 1048576, 1024, 131136, 65536, 1024, 1};
  if (n_in != 14) return;
  for (int i = 0; i < 14; ++i)
    if (in_sizes[i] != expect[i]) return;

  char* ws = (char*)d_ws;
  int*    flag   = (int*)ws;                     // 4B
  float*  am32   = (float*)(ws + 1024);          // [4096]
  float*  b32    = (float*)(ws + 17408);         // bq|bk|bv|bo  [4][1024]
  float*  zg32   = (float*)(ws + 33792);         // [1024]
  float*  ga32   = (float*)(ws + 37888);         // [1]
  __bf16* MgT16  = (__bf16*)(ws + 38912);        // [16][64][64] M^T, ends 169984
  __bf16* rel16  = (__bf16*)(ws + 301056);       // [131136], ends 563328
  __bf16* hs_pr  = (__bf16*)(ws + 565248);       // [2048][1024] per pair, ends 4759552
  __bf16* WT16   = (__bf16*)(ws + 4759552);      // 4x Wt [n][k], ends 13148160
  __bf16* qkv2   = (__bf16*)(ws + 13148160);     // [2048][3072], ends 25731072
  __bf16* comb2  = (__bf16*)(ws + 25731072);     // [2048][1024], ends 29925376
  __bf16* Vt2    = (__bf16*)(ws + 29925376);     // [2][16][64][1024], ends 34119680

  detect_k<<<1, 256, 0, stream>>>((const uint32_t*)d_in[0], flag);

  // one merged launch for all small tensors
  mono_cvt_k<<<806, 256, 0, stream>>>(d_in[1], d_in[3], d_in[5], d_in[7], d_in[9],
                                      d_in[12], d_in[13], d_in[10], d_in[11],
                                      am32, b32, zg32, ga32, rel16, MgT16, flag);
  const int widx[4] = {2, 4, 6, 8};
  for (int j = 0; j < 4; ++j)
    cvt_wT_k<<<dim3(32, 32), dim3(32, 8), 0, stream>>>(d_in[widx[j]],
                                                       WT16 + (size_t)j * 1048576, flag);

  for (int pr = 0; pr < 2; ++pr) {
    cvt_hs_k<<<8192, 256, 0, stream>>>(d_in[0], (size_t)pr * 2097152, hs_pr,
                                       2097152, flag);
    gemm_bt_k<<<dim3(16, 24), 256, 0, stream>>>(hs_pr, WT16, b32, qkv2,
                                                2048, 3072, 1024, 3072);
    vt2_k<<<dim3(16, 16, 2), 256, 0, stream>>>(qkv2, Vt2);
    attn_fused_k<<<dim3(16, 32), 256, 0, stream>>>(
        qkv2, Vt2, am32 + pr * 2048, rel16, MgT16, zg32, ga32, comb2);
    gemm_bt_out_k<<<dim3(16, 8), 256, 0, stream>>>(
        comb2, WT16 + 3 * 1048576, b32 + 3072, d_out, 2048, 1024, 1024,
        pr * 2048, flag);
  }
}

// Round 29
// 252.125 us; speedup vs baseline: 1.1147x; 1.0194x over previous
//
#include <hip/hip_runtime.h>
#include <cstdint>
#include <cstddef>

typedef __bf16 bf16x8 __attribute__((ext_vector_type(8)));
typedef float f32x4 __attribute__((ext_vector_type(4)));

static __device__ __forceinline__ f32x4 mfma16(bf16x8 a, bf16x8 b, f32x4 c) {
  return __builtin_amdgcn_mfma_f32_16x16x32_bf16(a, b, c, 0, 0, 0);
}

// LAW (R19/R20 proven): compute kernels must NEVER vector-load from d_in —
// d_in is only touched by scalar-load kernels; all bf16x8 loads hit ws.

// ---------------- input dtype sniffing (proven) ----------------
__global__ __launch_bounds__(256) void detect_k(const uint32_t* __restrict__ hs,
                                                int* __restrict__ flag) {
  __shared__ int cnt;
  if (threadIdx.x == 0) cnt = 0;
  __syncthreads();
  uint32_t w = hs[threadIdx.x];
  int b = (w >> 8) & 0x7F;
  if (b >= 0x3C && b <= 0x40) atomicAdd(&cnt, 1);
  __syncthreads();
  if (threadIdx.x == 0) *flag = (cnt >= 128) ? 1 : 0;
}

static __device__ __forceinline__ float ld_in(const void* p, size_t i, int f) {
  return f ? (float)((const __bf16*)p)[i] : ((const float*)p)[i];
}

// ---------------- merged small-tensor converter (R28-proven) ----------------
__global__ __launch_bounds__(256) void mono_cvt_k(const void* __restrict__ amask,
                                                  const void* __restrict__ bq,
                                                  const void* __restrict__ bk,
                                                  const void* __restrict__ bv,
                                                  const void* __restrict__ bo,
                                                  const void* __restrict__ zg,
                                                  const void* __restrict__ ga,
                                                  const void* __restrict__ rel,
                                                  const void* __restrict__ Mg,
                                                  float* __restrict__ am32,
                                                  float* __restrict__ b32,
                                                  float* __restrict__ zg32,
                                                  float* __restrict__ ga32,
                                                  __bf16* __restrict__ rel16,
                                                  __bf16* __restrict__ MgT16,
                                                  const int* __restrict__ flag) {
  const int f = *flag;
  const int b = blockIdx.x, t = threadIdx.x;
  if (b < 16) {
    int i = b * 256 + t;
    am32[i] = ld_in(amask, i, f);
  } else if (b < 32) {
    int i = (b - 16) * 256 + t;
    const void* src = (i < 1024) ? bq : (i < 2048) ? bk : (i < 3072) ? bv : bo;
    b32[i] = ld_in(src, i & 1023, f);
  } else if (b < 36) {
    int i = (b - 32) * 256 + t;
    zg32[i] = ld_in(zg, i, f);
  } else if (b == 36) {
    if (t == 0) ga32[0] = ld_in(ga, 0, f);
  } else if (b < 550) {
    int i = (b - 37) * 256 + t;
    if (i < 131136) rel16[i] = (__bf16)ld_in(rel, i, f);
  } else {
    int i = (b - 550) * 256 + t;
    if (i < 65536) {
      int h = i >> 12, rem = i & 4095, e = rem >> 6, d = rem & 63;
      MgT16[i] = (__bf16)ld_in(Mg, (size_t)h * 4096 + d * 64 + e, f);
    }
  }
}

// hs pair converter (scalar d_in reads)
__global__ __launch_bounds__(256) void cvt_hs_k(const void* __restrict__ src,
                                                size_t srcOff,
                                                __bf16* __restrict__ dst, int n,
                                                const int* __restrict__ flag) {
  int i = blockIdx.x * 256 + threadIdx.x;
  if (i >= n) return;
  dst[i] = (__bf16)ld_in(src, srcOff + i, *flag);
}

// Transposing weight converter (R24-proven): W -> Wt[n][k] in ws.
__global__ void cvt_wT_k(const void* __restrict__ W, __bf16* __restrict__ T,
                         const int* __restrict__ flag) {
  __shared__ __bf16 t[32][33];
  int k0 = blockIdx.x * 32, n0 = blockIdx.y * 32;
  int tx = threadIdx.x, ty = threadIdx.y;
  int f = *flag;
#pragma unroll
  for (int i = 0; i < 32; i += 8)
    t[ty + i][tx] = (__bf16)ld_in(W, (size_t)(k0 + ty + i) * 1024 + n0 + tx, f);
  __syncthreads();
#pragma unroll
  for (int i = 0; i < 32; i += 8)
    T[(size_t)(n0 + ty + i) * 1024 + k0 + tx] = t[tx][ty + i];
}

// ---------------- V transpose to global (R25-proven) ----------------
__global__ __launch_bounds__(256) void vt2_k(const __bf16* __restrict__ qkv2,
                                             __bf16* __restrict__ Vt2) {
  __shared__ __bf16 t[64][72];
  const int h = blockIdx.x, k0 = blockIdx.y * 64, bl = blockIdx.z;
  const int tid = threadIdx.x;
  const int r = tid >> 2, dc = (tid & 3) * 16;
  const __bf16* src = qkv2 + (size_t)(bl * 1024 + k0 + r) * 3072 + 2048 + h * 64 + dc;
  *(bf16x8*)(&t[r][dc]) = *(const bf16x8*)(src);
  *(bf16x8*)(&t[r][dc + 8]) = *(const bf16x8*)(src + 8);
  __syncthreads();
  const int dr = tid >> 2, kc = (tid & 3) * 16;
  __bf16* dst = Vt2 + ((size_t)(bl * 16 + h) * 64 + dr) * 1024 + k0 + kc;
  bf16x8 o0, o1;
#pragma unroll
  for (int j = 0; j < 8; ++j) { o0[j] = t[kc + j][dr]; o1[j] = t[kc + 8 + j][dr]; }
  *(bf16x8*)dst = o0;
  *(bf16x8*)(dst + 8) = o1;
}

// ---------------- m92 XOR-swizzled GEMM (R24-proven) ----------------
__global__ __launch_bounds__(256) void gemm_bt_k(const __bf16* __restrict__ A,
                                                 const __bf16* __restrict__ Bt,
                                                 const float* __restrict__ bias,
                                                 __bf16* __restrict__ C,
                                                 int M, int N, int K, int ldc) {
  const int tm = blockIdx.x * 128, tn = blockIdx.y * 128;
  const int tid = threadIdx.x;
  const int w = tid >> 6, l = tid & 63;
  const int l15 = l & 15, l4 = l >> 4;
  const int wm = (w >> 1) * 64, wn = (w & 1) * 64;
  __shared__ __bf16 As[128 * 64];
  __shared__ __bf16 Bs[128 * 64];
  f32x4 acc[4][4] = {};
  for (int kt = 0; kt < K; kt += 64) {
    __syncthreads();
#pragma unroll
    for (int i = 0; i < 4; ++i) {
      int c = tid + i * 256;
      int r = c >> 3, s = c & 7;
      int byt = r * 128 + ((s ^ (r & 7)) << 4);
      *(bf16x8*)((char*)As + byt) = *(const bf16x8*)(A + (size_t)(tm + r) * K + kt + s * 8);
      *(bf16x8*)((char*)Bs + byt) = *(const bf16x8*)(Bt + (size_t)(tn + r) * K + kt + s * 8);
    }
    __syncthreads();
#pragma unroll
    for (int kk = 0; kk < 2; ++kk) {
      bf16x8 af[4], bfr[4];
#pragma unroll
      for (int m = 0; m < 4; ++m) {
        int row = wm + m * 16 + l15;
        af[m] = *(const bf16x8*)((char*)As + row * 128 + (((l4 + 4 * kk) ^ (row & 7)) << 4));
      }
#pragma unroll
      for (int n = 0; n < 4; ++n) {
        int row = wn + n * 16 + l15;
        bfr[n] = *(const bf16x8*)((char*)Bs + row * 128 + (((l4 + 4 * kk) ^ (row & 7)) << 4));
      }
#pragma unroll
      for (int m = 0; m < 4; ++m)
#pragma unroll
        for (int n = 0; n < 4; ++n)
          acc[m][n] = mfma16(af[m], bfr[n], acc[m][n]);
    }
  }
#pragma unroll
  for (int m = 0; m < 4; ++m)
#pragma unroll
    for (int n = 0; n < 4; ++n) {
      int row = tm + wm + m * 16 + l4 * 4;
      int col = tn + wn + n * 16 + l15;
      float bb = bias[col];
#pragma unroll
      for (int r = 0; r < 4; ++r)
        C[(size_t)(row + r) * ldc + col] = (__bf16)(acc[m][n][r] + bb);
    }
}

__global__ __launch_bounds__(256) void gemm_bt_out_k(const __bf16* __restrict__ A,
                                                     const __bf16* __restrict__ Bt,
                                                     const float* __restrict__ bias,
                                                     void* __restrict__ out,
                                                     int M, int N, int K, int pairOff,
                                                     const int* __restrict__ flag) {
  const int tm = blockIdx.x * 128, tn = blockIdx.y * 128;
  const int tid = threadIdx.x;
  const int w = tid >> 6, l = tid & 63;
  const int l15 = l & 15, l4 = l >> 4;
  const int wm = (w >> 1) * 64, wn = (w & 1) * 64;
  __shared__ __bf16 As[128 * 64];
  __shared__ __bf16 Bs[128 * 64];
  f32x4 acc[4][4] = {};
  for (int kt = 0; kt < K; kt += 64) {
    __syncthreads();
#pragma unroll
    for (int i = 0; i < 4; ++i) {
      int c = tid + i * 256;
      int r = c >> 3, s = c & 7;
      int byt = r * 128 + ((s ^ (r & 7)) << 4);
      *(bf16x8*)((char*)As + byt) = *(const bf16x8*)(A + (size_t)(tm + r) * K + kt + s * 8);
      *(bf16x8*)((char*)Bs + byt) = *(const bf16x8*)(Bt + (size_t)(tn + r) * K + kt + s * 8);
    }
    __syncthreads();
#pragma unroll
    for (int kk = 0; kk < 2; ++kk) {
      bf16x8 af[4], bfr[4];
#pragma unroll
      for (int m = 0; m < 4; ++m) {
        int row = wm + m * 16 + l15;
        af[m] = *(const bf16x8*)((char*)As + row * 128 + (((l4 + 4 * kk) ^ (row & 7)) << 4));
      }
#pragma unroll
      for (int n = 0; n < 4; ++n) {
        int row = wn + n * 16 + l15;
        bfr[n] = *(const bf16x8*)((char*)Bs + row * 128 + (((l4 + 4 * kk) ^ (row & 7)) << 4));
      }
#pragma unroll
      for (int m = 0; m < 4; ++m)
#pragma unroll
        for (int n = 0; n < 4; ++n)
          acc[m][n] = mfma16(af[m], bfr[n], acc[m][n]);
    }
  }
  int use16 = *flag;
#pragma unroll
  for (int m = 0; m < 4; ++m)
#pragma unroll
    for (int n = 0; n < 4; ++n) {
      int row = tm + wm + m * 16 + l4 * 4;
      int col = tn + wn + n * 16 + l15;
      float bb = bias[col];
#pragma unroll
      for (int r = 0; r < 4; ++r) {
        float v = acc[m][n][r] + bb;
        size_t idx = (size_t)(pairOff + row + r) * N + col;
        if (use16) ((__bf16*)out)[idx] = (__bf16)v;
        else       ((float*)out)[idx] = v;
      }
    }
}

// ---------------- MFMA fused attention (R25 body) + T1 XCD swizzle ----------------
// 1D grid of 512: bid = qt*32 + bh  =>  bid%8 == bh%8, so all 16 q-tiles of a
// (bl,h) pair land on ONE XCD -> its K/V panel (~320 KB) stays in that XCD's L2.
__global__ __launch_bounds__(256) void attn_fused_k(const __bf16* __restrict__ QKV2,
                                                    const __bf16* __restrict__ Vt2,
                                                    const float* __restrict__ amask,
                                                    const __bf16* __restrict__ rel16,
                                                    const __bf16* __restrict__ MgT16,
                                                    const float* __restrict__ zg32,
                                                    const float* __restrict__ ga32,
                                                    __bf16* __restrict__ comb) {
  const int bid = blockIdx.x;
  const int qt = bid >> 5, bh = bid & 31;     // T1 swizzle (perf-only remap)
  const int bl = bh >> 4, h = bh & 15;
  const int tid = threadIdx.x;
  const int w = tid >> 6, l = tid & 63;
  const int l15 = l & 15, l4 = l >> 4;
  const int q0 = qt * 64;
  const __bf16* QKVb = QKV2 + (size_t)bl * 1024 * 3072;
  const __bf16* VtH = Vt2 + (size_t)(bl * 16 + h) * 64 * 1024;

  __shared__ __bf16 Kt[64][72];
  __shared__ __bf16 VtT[64][72];
  __shared__ __bf16 Pl[4][16 * 72];
  __shared__ float RKb[128 * 66];
  __shared__ float maskv[64];
  __shared__ float denv[64];

  bf16x8 qf[2];
#pragma unroll
  for (int kk = 0; kk < 2; ++kk)
    qf[kk] = *(const bf16x8*)(QKVb + (size_t)(q0 + w * 16 + l15) * 3072 + h * 64 +
                              l4 * 8 + kk * 32);

  f32x4 accO[4] = {};
  float mrun[4], lrun[4];
#pragma unroll
  for (int r = 0; r < 4; ++r) { mrun[r] = -3.0e38f; lrun[r] = 0.f; }

  for (int kt = 0; kt < 16; ++kt) {
    const int k0 = kt * 64;
    __syncthreads();
#pragma unroll
    for (int i = 0; i < 2; ++i) {
      int c = tid + i * 256;
      int kr = c >> 3, s = (c & 7) * 8;
      *(bf16x8*)(&Kt[kr][s]) =
          *(const bf16x8*)(QKVb + (size_t)(k0 + kr) * 3072 + 1024 + h * 64 + s);
      *(bf16x8*)(&VtT[kr][s]) = *(const bf16x8*)(VtH + (size_t)kr * 1024 + k0 + s);
    }
    if (tid < 64) maskv[tid] = amask[bl * 1024 + k0 + tid];
    __syncthreads();

    const int jb = q0 - k0 - 63 + 1024;
#pragma unroll
    for (int ms = 0; ms < 2; ++ms) {
      f32x4 rk[4] = {};
#pragma unroll
      for (int kk = 0; kk < 2; ++kk) {
        bf16x8 ea = *(const bf16x8*)(rel16 + (size_t)(jb + w * 32 + ms * 16 + l15) * 64 +
                                     l4 * 8 + kk * 32);
#pragma unroll
        for (int nb = 0; nb < 4; ++nb) {
          bf16x8 kb = *(const bf16x8*)(&Kt[nb * 16 + l15][l4 * 8 + kk * 32]);
          rk[nb] = mfma16(ea, kb, rk[nb]);
        }
      }
#pragma unroll
      for (int nb = 0; nb < 4; ++nb)
#pragma unroll
        for (int r = 0; r < 4; ++r)
          RKb[(w * 32 + ms * 16 + l4 * 4 + r) * 66 + nb * 16 + l15] = rk[nb][r];
    }
    __syncthreads();

    f32x4 sacc[4] = {};
#pragma unroll
    for (int kk = 0; kk < 2; ++kk)
#pragma unroll
      for (int nb = 0; nb < 4; ++nb) {
        bf16x8 kb = *(const bf16x8*)(&Kt[nb * 16 + l15][l4 * 8 + kk * 32]);
        sacc[nb] = mfma16(qf[kk], kb, sacc[nb]);
      }

    float p[4][4];
    float tmax[4];
#pragma unroll
    for (int r = 0; r < 4; ++r) tmax[r] = -3.0e38f;
#pragma unroll
    for (int nb = 0; nb < 4; ++nb) {
      int kloc = nb * 16 + l15;
      float mk = maskv[kloc] * (-1e9f);
#pragma unroll
      for (int r = 0; r < 4; ++r) {
        int jl = (w * 16 + l4 * 4 + r) - kloc + 63;
        float s = (sacc[nb][r] + RKb[jl * 66 + kloc]) * 0.125f + mk;
        p[nb][r] = s;
        tmax[r] = fmaxf(tmax[r], s);
      }
    }
#pragma unroll
    for (int x = 1; x < 16; x <<= 1)
#pragma unroll
      for (int r = 0; r < 4; ++r) tmax[r] = fmaxf(tmax[r], __shfl_xor(tmax[r], x, 64));
    float al[4];
#pragma unroll
    for (int r = 0; r < 4; ++r) {
      float mn = fmaxf(mrun[r], tmax[r]);
      al[r] = __expf(mrun[r] - mn);
      mrun[r] = mn;
    }
    float rs[4] = {0.f, 0.f, 0.f, 0.f};
#pragma unroll
    for (int nb = 0; nb < 4; ++nb)
#pragma unroll
      for (int r = 0; r < 4; ++r) {
        p[nb][r] = __expf(p[nb][r] - mrun[r]);
        rs[r] += p[nb][r];
      }
#pragma unroll
    for (int x = 1; x < 16; x <<= 1)
#pragma unroll
      for (int r = 0; r < 4; ++r) rs[r] += __shfl_xor(rs[r], x, 64);
#pragma unroll
    for (int r = 0; r < 4; ++r) lrun[r] = lrun[r] * al[r] + rs[r];
#pragma unroll
    for (int nb = 0; nb < 4; ++nb)
#pragma unroll
      for (int r = 0; r < 4; ++r) accO[nb][r] *= al[r];

#pragma unroll
    for (int nb = 0; nb < 4; ++nb)
#pragma unroll
      for (int r = 0; r < 4; ++r)
        Pl[w][(l4 * 4 + r) * 72 + nb * 16 + l15] = (__bf16)p[nb][r];
    __syncthreads();

#pragma unroll
    for (int kk = 0; kk < 2; ++kk) {
      bf16x8 pa = *(const bf16x8*)(&Pl[w][l15 * 72 + kk * 32 + l4 * 8]);
#pragma unroll
      for (int nb = 0; nb < 4; ++nb) {
        bf16x8 vb = *(const bf16x8*)(&VtT[nb * 16 + l15][kk * 32 + l4 * 8]);
        accO[nb] = mfma16(pa, vb, accO[nb]);
      }
    }
  }

#pragma unroll
  for (int nb = 0; nb < 4; ++nb)
#pragma unroll
    for (int r = 0; r < 4; ++r) accO[nb][r] /= lrun[r];

  // ---- epilogue (overlays RKb); Mtb staged vector from MgT16 ----
  __syncthreads();
  __bf16* sqb = (__bf16*)RKb;
  __bf16* Mtb = ((__bf16*)RKb) + 64 * 72;
#pragma unroll
  for (int i = 0; i < 2; ++i) {
    int c = tid + i * 256;
    int qr = c >> 3, s = (c & 7) * 8;
    bf16x8 qv = *(const bf16x8*)(QKVb + (size_t)(q0 + qr) * 3072 + h * 64 + s);
#pragma unroll
    for (int j = 0; j < 8; ++j) {
      float x = (float)qv[j];
      sqb[qr * 72 + s + j] = (__bf16)(x > 0.f ? x + 1.f : __expf(x));
    }
    bf16x8 mv = *(const bf16x8*)(MgT16 + (size_t)h * 4096 + qr * 64 + s);
    *(bf16x8*)(&Mtb[qr * 72 + s]) = mv;
  }
  __syncthreads();
  if (tid < 64) {
    float sden = 0.f;
    const float* zp = zg32 + h * 64;
#pragma unroll
    for (int d = 0; d < 64; ++d) sden += (float)sqb[tid * 72 + d] * zp[d];
    denv[tid] = sden + 1e-6f;
  }
  __syncthreads();
  float gate = 1.f / (1.f + __expf(-ga32[0]));
  f32x4 nacc[4] = {};
#pragma unroll
  for (int kk = 0; kk < 2; ++kk) {
    bf16x8 sa = *(const bf16x8*)(sqb + (w * 16 + l15) * 72 + kk * 32 + l4 * 8);
#pragma unroll
    for (int nb = 0; nb < 4; ++nb) {
      bf16x8 mb = *(const bf16x8*)(Mtb + (nb * 16 + l15) * 72 + kk * 32 + l4 * 8);
      nacc[nb] = mfma16(sa, mb, nacc[nb]);
    }
  }
#pragma unroll
  for (int nb = 0; nb < 4; ++nb)
#pragma unroll
    for (int r = 0; r < 4; ++r) {
      int qrel = w * 16 + l4 * 4 + r;
      float gl = nacc[nb][r] / denv[qrel];
      float cv = gate * accO[nb][r] + (1.f - gate) * gl;
      comb[(size_t)(bl * 1024 + q0 + qrel) * 1024 + h * 64 + nb * 16 + l15] = (__bf16)cv;
    }
}

// ---------------- launcher ----------------
extern "C" void kernel_launch(void* const* d_in, const int* in_sizes, int n_in,
                              void* d_out, int out_size, void* d_ws, size_t ws_size,
                              hipStream_t stream) {
  const int expect[14] = {4194304, 4096, 1048576, 1024, 1048576, 1024, 1048576,
                          1024, 1048576, 1024, 131136, 65536, 1024, 1};
  if (n_in != 14) return;
  for (int i = 0; i < 14; ++i)
    if (in_sizes[i] != expect[i]) return;

  char* ws = (char*)d_ws;
  int*    flag   = (int*)ws;                     // 4B
  float*  am32   = (float*)(ws + 1024);          // [4096]
  float*  b32    = (float*)(ws + 17408);         // bq|bk|bv|bo  [4][1024]
  float*  zg32   = (float*)(ws + 33792);         // [1024]
  float*  ga32   = (float*)(ws + 37888);         // [1]
  __bf16* MgT16  = (__bf16*)(ws + 38912);        // [16][64][64] M^T, ends 169984
  __bf16* rel16  = (__bf16*)(ws + 301056);       // [131136], ends 563328
  __bf16* hs_pr  = (__bf16*)(ws + 565248);       // [2048][1024] per pair, ends 4759552
  __bf16* WT16   = (__bf16*)(ws + 4759552);      // 4x Wt [n][k], ends 13148160
  __bf16* qkv2   = (__bf16*)(ws + 13148160);     // [2048][3072], ends 25731072
  __bf16* comb2  = (__bf16*)(ws + 25731072);     // [2048][1024], ends 29925376
  __bf16* Vt2    = (__bf16*)(ws + 29925376);     // [2][16][64][1024], ends 34119680

  detect_k<<<1, 256, 0, stream>>>((const uint32_t*)d_in[0], flag);

  mono_cvt_k<<<806, 256, 0, stream>>>(d_in[1], d_in[3], d_in[5], d_in[7], d_in[9],
                                      d_in[12], d_in[13], d_in[10], d_in[11],
                                      am32, b32, zg32, ga32, rel16, MgT16, flag);
  const int widx[4] = {2, 4, 6, 8};
  for (int j = 0; j < 4; ++j)
    cvt_wT_k<<<dim3(32, 32), dim3(32, 8), 0, stream>>>(d_in[widx[j]],
                                                       WT16 + (size_t)j * 1048576, flag);

  for (int pr = 0; pr < 2; ++pr) {
    cvt_hs_k<<<8192, 256, 0, stream>>>(d_in[0], (size_t)pr * 2097152, hs_pr,
                                       2097152, flag);
    gemm_bt_k<<<dim3(16, 24), 256, 0, stream>>>(hs_pr, WT16, b32, qkv2,
                                                2048, 3072, 1024, 3072);
    vt2_k<<<dim3(16, 16, 2), 256, 0, stream>>>(qkv2, Vt2);
    attn_fused_k<<<512, 256, 0, stream>>>(
        qkv2, Vt2, am32 + pr * 2048, rel16, MgT16, zg32, ga32, comb2);
    gemm_bt_out_k<<<dim3(16, 8), 256, 0, stream>>>(
        comb2, WT16 + 3 * 1048576, b32 + 3072, d_out, 2048, 1024, 1024,
        pr * 2048, flag);
  }
}